// Round 5
// baseline (107.473 us; speedup 1.0000x reference)
//
#include <hip/hip_runtime.h>
#include <math.h>

typedef float v2f __attribute__((ext_vector_type(2)));

#define NN 1024
#define IN_F 256
#define OUT_F 128
#define NHEADS 4
#define NHF 32

// K1: g_l/g_r = h @ W^T. Grid (16 row-groups, 32 col-sets) = 512 blocks (2/CU).
// Block 256 thr = 4 waves; lane <-> row (64 rows), wave <-> 2 cols (8 cols/block).
// h-tile staged in LDS, stride 132 dwords (132%32==4 -> lane-strided b128 reads
// hit the 8-dword/bank floor = conflict-free). W pointer is wave-uniform
// (readfirstlane) -> scalar loads, or worst-case same-address vector loads
// (1 line/inst) -- never the 64-lines/inst lane-scatter of prior rounds.
// Outputs: gl TRANSPOSED as [h][fpair(16)][j] float2 (for K2 coalesced reads),
// gr as [h][j][f] (for K2 Phase-C tiling).
__global__ void __launch_bounds__(256) glr_gemm(const float* __restrict__ hmat,
                                                const float* __restrict__ Wl,
                                                const float* __restrict__ Wr,
                                                v2f* __restrict__ glT,
                                                float* __restrict__ grh) {
    __shared__ float hs[64 * 132];   // 33.8 KB
    const int tid  = threadIdx.x;
    const int rg   = blockIdx.x;     // 0..15
    const int cs   = blockIdx.y;     // 0..31
    const int lane = tid & 63;
    const int wu   = __builtin_amdgcn_readfirstlane(tid >> 6);
    const int c0   = cs * 8 + wu * 2;           // global col pair (0..254, even)
    const int half = c0 >> 7;                   // 0 -> Wl/gl, 1 -> Wr/gr
    const int cc   = c0 & 127;
    const float* __restrict__ W   = half ? Wr : Wl;
    const float* __restrict__ wr0 = W + cc * IN_F;
    const float* __restrict__ wr1 = wr0 + IN_F;

    float a0 = 0.f, a1 = 0.f;
    for (int kh = 0; kh < 2; ++kh) {
        // stage 64 rows x 128 k, coalesced
#pragma unroll
        for (int s = 0; s < 8; ++s) {
            const int v = tid + s * 256;        // f4 units: row*32 + q
            const int row = v >> 5, q = v & 31;
            const float4 x = ((const float4*)hmat)[(rg * 64 + row) * 64 + kh * 32 + q];
            *(float4*)(hs + row * 132 + q * 4) = x;
        }
        __syncthreads();
        const float4* __restrict__ w0p = (const float4*)(wr0 + kh * 128);
        const float4* __restrict__ w1p = (const float4*)(wr1 + kh * 128);
        const float*  __restrict__ hrow = hs + lane * 132;
#pragma unroll 8
        for (int q = 0; q < 32; ++q) {
            const float4 hv = *(const float4*)(hrow + q * 4);
            const float4 w0 = w0p[q];
            const float4 w1 = w1p[q];
            a0 = fmaf(hv.x, w0.x, fmaf(hv.y, w0.y, fmaf(hv.z, w0.z, fmaf(hv.w, w0.w, a0))));
            a1 = fmaf(hv.x, w1.x, fmaf(hv.y, w1.y, fmaf(hv.z, w1.z, fmaf(hv.w, w1.w, a1))));
        }
        __syncthreads();
    }

    const int row = rg * 64 + lane;
    const int hh = cc >> 5, f0 = cc & 31;
    if (half == 0) {
        glT[(hh * 16 + (f0 >> 1)) * NN + row] = (v2f){a0, a1};   // lane-contiguous
    } else {
        *(v2f*)(grh + (hh * NN + row) * NHF + f0) = (v2f){a0, a1};
    }
}

// K2: one block per (i-tile of 8, head); 512 thr, ~66 KB LDS (2 blocks/CU).
// Phase A: e = 0.6*alpha_j + 0.4*sum_f w_f|gl+gr| (beta cancels; e is O(1) so
//   no max pass). gl from glT coalesced; packed f32 math (pk_add/pk_max/pk_fma).
//   p = adj?exp(e):0 -> p_buf[j][8ii] (stride 12, bank-optimal b128 writes).
// Phase C: register tile 8ii x 4f per lane; wave <-> f-quad (disjoint f -> no
//   cross-wave reduction), lane <-> j; g_r staged in 128-j LDS tiles (stride 36).
//   Epilogue: 6-round butterfly, lane0 stores /l + ELU.
__global__ void __launch_bounds__(512, 4) gat_main(const v2f* __restrict__ glT,
                                                   const float* __restrict__ grh,
                                                   const int* __restrict__ adj,
                                                   const float* __restrict__ attn_w,
                                                   float* __restrict__ out) {
    const int hh  = blockIdx.y;
    const int i0  = blockIdx.x * 8;
    const int tid = threadIdx.x;

    __shared__ float p_buf[NN * 12];   // 48 KB, [j][ii(8)+pad4]
    __shared__ float g_t[128 * 36];    // 18 KB, [j][f(32)+pad4]
    __shared__ float red[8][8];
    __shared__ float l_sh[8];

    const v2f* __restrict__ w2p = (const v2f*)attn_w;

    float lpart[8];
#pragma unroll
    for (int ii = 0; ii < 8; ++ii) lpart[ii] = 0.f;

    // ---- Phase A ----
    for (int c = 0; c < 2; ++c) {
        const int j = (c << 9) + tid;
        const v2f* __restrict__ glp = glT + hh * 16 * NN + j;
        v2f gl2[16];
#pragma unroll
        for (int fp = 0; fp < 16; ++fp) gl2[fp] = glp[fp * NN];   // coalesced

        v2f aa = {0.f, 0.f};
#pragma unroll
        for (int fp = 0; fp < 16; ++fp) aa += gl2[fp] * w2p[fp];
        const float alpha6 = 0.6f * (aa.x + aa.y);

        int adjv[8];
#pragma unroll
        for (int ii = 0; ii < 8; ++ii) adjv[ii] = adj[(i0 + ii) * NN + j];

        float pv[8];
#pragma unroll
        for (int ii = 0; ii < 8; ++ii) {
            const v2f* __restrict__ gr2 = (const v2f*)(grh + (hh * NN + i0 + ii) * NHF);
            v2f S = {0.f, 0.f};
#pragma unroll
            for (int fp = 0; fp < 16; ++fp) {
                const v2f s = gl2[fp] + gr2[fp];                 // uniform -> s_load
                const v2f m = __builtin_elementwise_max(s, -s);  // pk_max w/ neg
                S += m * w2p[fp];
            }
            const float e = fmaf(0.4f, S.x + S.y, alpha6);
            const float p = adjv[ii] ? __expf(e) : 0.f;
            pv[ii] = p;
            lpart[ii] += p;
        }
        float4 wA; wA.x = pv[0]; wA.y = pv[1]; wA.z = pv[2]; wA.w = pv[3];
        float4 wB; wB.x = pv[4]; wB.y = pv[5]; wB.z = pv[6]; wB.w = pv[7];
        *(float4*)&p_buf[j * 12]     = wA;
        *(float4*)&p_buf[j * 12 + 4] = wB;
    }

    // ---- Phase B: row sums ----
    const int lane = tid & 63, wv = tid >> 6;
#pragma unroll
    for (int ii = 0; ii < 8; ++ii) {
        float v = lpart[ii];
#pragma unroll
        for (int d = 32; d > 0; d >>= 1) v += __shfl_xor(v, d);
        if (lane == 0) red[ii][wv] = v;
    }
    __syncthreads();
    if (tid < 8) {
        float l = red[tid][0];
#pragma unroll
        for (int w = 1; w < 8; ++w) l += red[tid][w];
        l_sh[tid] = l;
    }
    __syncthreads();

    // ---- Phase C ----
    v2f acc[8][2];
#pragma unroll
    for (int ii = 0; ii < 8; ++ii) { acc[ii][0] = (v2f){0.f, 0.f}; acc[ii][1] = (v2f){0.f, 0.f}; }

    for (int t = 0; t < 8; ++t) {
        const float4* __restrict__ src = (const float4*)(grh + (hh * NN + t * 128) * NHF);
#pragma unroll
        for (int s2 = 0; s2 < 2; ++s2) {
            const int u = tid + s2 * 512;            // 1024 float4 = 128j x 32f
            const int jj = u >> 3, f4 = u & 7;
            const float4 x = src[u];
            *(float4*)&g_t[jj * 36 + f4 * 4] = x;
        }
        __syncthreads();
#pragma unroll
        for (int u2 = 0; u2 < 2; ++u2) {
            const int jl = lane + (u2 << 6);
            const float* __restrict__ pb = &p_buf[(t * 128 + jl) * 12];
            const float4 pA = *(const float4*)pb;
            const float4 pB = *(const float4*)(pb + 4);
            const float4 g  = *(const float4*)&g_t[jl * 36 + wv * 4];
            const v2f g01 = {g.x, g.y}, g23 = {g.z, g.w};
            acc[0][0] += (v2f){pA.x, pA.x} * g01;  acc[0][1] += (v2f){pA.x, pA.x} * g23;
            acc[1][0] += (v2f){pA.y, pA.y} * g01;  acc[1][1] += (v2f){pA.y, pA.y} * g23;
            acc[2][0] += (v2f){pA.z, pA.z} * g01;  acc[2][1] += (v2f){pA.z, pA.z} * g23;
            acc[3][0] += (v2f){pA.w, pA.w} * g01;  acc[3][1] += (v2f){pA.w, pA.w} * g23;
            acc[4][0] += (v2f){pB.x, pB.x} * g01;  acc[4][1] += (v2f){pB.x, pB.x} * g23;
            acc[5][0] += (v2f){pB.y, pB.y} * g01;  acc[5][1] += (v2f){pB.y, pB.y} * g23;
            acc[6][0] += (v2f){pB.z, pB.z} * g01;  acc[6][1] += (v2f){pB.z, pB.z} * g23;
            acc[7][0] += (v2f){pB.w, pB.w} * g01;  acc[7][1] += (v2f){pB.w, pB.w} * g23;
        }
        __syncthreads();
    }

    // butterfly over 64 lanes (waves own disjoint f-quads -> no cross-wave step)
    float o32[32];
#pragma unroll
    for (int ii = 0; ii < 8; ++ii) {
        o32[ii * 4 + 0] = acc[ii][0].x;  o32[ii * 4 + 1] = acc[ii][0].y;
        o32[ii * 4 + 2] = acc[ii][1].x;  o32[ii * 4 + 3] = acc[ii][1].y;
    }
#pragma unroll
    for (int d = 32; d > 0; d >>= 1) {
#pragma unroll
        for (int k = 0; k < 32; ++k) o32[k] += __shfl_xor(o32[k], d);
    }
    if (lane == 0) {
#pragma unroll
        for (int ii = 0; ii < 8; ++ii) {
            const float inv = 1.f / l_sh[ii];
            float x0 = o32[ii * 4 + 0] * inv;
            float x1 = o32[ii * 4 + 1] * inv;
            float x2 = o32[ii * 4 + 2] * inv;
            float x3 = o32[ii * 4 + 3] * inv;
            float4 r;
            r.x = (x0 > 0.f) ? x0 : (__expf(x0) - 1.f);
            r.y = (x1 > 0.f) ? x1 : (__expf(x1) - 1.f);
            r.z = (x2 > 0.f) ? x2 : (__expf(x2) - 1.f);
            r.w = (x3 > 0.f) ? x3 : (__expf(x3) - 1.f);
            *(float4*)(out + (i0 + ii) * OUT_F + hh * NHF + wv * 4) = r;
        }
    }
}

extern "C" void kernel_launch(void* const* d_in, const int* in_sizes, int n_in,
                              void* d_out, int out_size, void* d_ws, size_t ws_size,
                              hipStream_t stream) {
    const float* hmat = (const float*)d_in[0];
    const int*   adj  = (const int*)d_in[1];
    const float* Wl   = (const float*)d_in[2];
    const float* Wr   = (const float*)d_in[3];
    const float* aw   = (const float*)d_in[4];
    float* o          = (float*)d_out;

    float* wsf = (float*)d_ws;
    v2f*   glT = (v2f*)wsf;                        // [4][16][1024] float2 = 512 KB
    float* grh = wsf + NHEADS * 16 * NN * 2;       // [4][1024][32] = 512 KB

    glr_gemm<<<dim3(16, 32), dim3(256), 0, stream>>>(hmat, Wl, Wr, glT, grh);
    gat_main<<<dim3(NN / 8, NHEADS), dim3(512), 0, stream>>>(glT, grh, adj, aw, o);
}